// Round 8
// baseline (838.372 us; speedup 1.0000x reference)
//
#include <hip/hip_runtime.h>
#include <hip/hip_cooperative_groups.h>

namespace cg = cooperative_groups;

#define N_NODES 50000
#define C_FEAT  64
#define E_EDGES 800000
#define KEYS    400000          // dst*8 + t
#define NCHUNK  782             // ceil(KEYS/512)
#define NTILE_CONV 3125         // N/16
#define NTILE_ADV  1563         // ceil(N/32)
#define SMEM_BYTES 25856        // max(conv 16640, adv 25600, scan 3200)

typedef __attribute__((ext_vector_type(8))) short short8;
typedef __attribute__((ext_vector_type(4))) float f32x4;

__device__ __forceinline__ float bf2f(unsigned short u) {
    union { unsigned int i; float f; } v; v.i = ((unsigned int)u) << 16; return v.f;
}
__device__ __forceinline__ unsigned short f2bf(float f) {
    union { float f; unsigned int i; } v; v.f = f;
    unsigned int r = v.i + 0x7fff + ((v.i >> 16) & 1);   // RNE
    return (unsigned short)(r >> 16);
}

struct MegaParams {
    const float *x, *Wt1, *bt1, *Wt2, *bt2, *Wa1, *ba1, *Wa2, *ba2;
    const int *src, *dst, *tix;
    float *out, *h1, *h2;
    unsigned short *xb, *h1b, *WT1, *WT2;
    int *cnt, *bsum, *elist;
};

// ---- conv phase: t-sorted register-stream gather (branchless flush) -> MFMA ----
#define EDGE(K) int p##K = __builtin_amdgcn_readlane(pv, e + K);                      \
                float v##K = bf2f(Xb[(size_t)(p##K & 0xffff) * 64 + c]);
#define BFL(K)  { int _t = p##K >> 16;                                                \
                  scat[dl][cur * 64 + c] = f2bf(acc);                                 \
                  acc = (_t != cur) ? v##K : (acc + v##K);                            \
                  cur = _t; }

__device__ __forceinline__ void conv_phase(const unsigned short* __restrict__ Xb,
                                           const unsigned short* __restrict__ WT,
                                           const float* __restrict__ bias,
                                           const int* __restrict__ segend,
                                           const int* __restrict__ elist,
                                           float* __restrict__ H,
                                           unsigned short* __restrict__ Hb,
                                           int writeHb,
                                           unsigned char* smem,
                                           int lane, int wave, int bid, int nblocks) {
    unsigned short (*scat)[520] = (unsigned short(*)[520])smem;
    const int c = lane;
    for (int tile = bid; tile < NTILE_CONV; tile += nblocks) {
        const int dbase = tile * 16;
        {   // zero own rows (wave-private in stage 1)
            short8 z = {};
            #pragma unroll
            for (int z4 = 0; z4 < 4; ++z4)
                *(short8*)&scat[wave * 4 + z4][lane * 8] = z;
        }
        #pragma unroll
        for (int q = 0; q < 4; ++q) {
            const int dl = wave * 4 + q;
            const int d = dbase + dl;
            int i = (d == 0) ? 0 : segend[d * 8 - 1];
            const int end = segend[d * 8 + 7];
            int cur = 0;
            float acc = 0.f;
            while (i < end) {
                int cnt = end - i; cnt = (cnt > 64) ? 64 : cnt;
                int pv = (lane < cnt) ? elist[i + lane] : 0;   // 1 coalesced load / 64 edges
                int e = 0;
                for (; e + 7 < cnt; e += 8) {
                    EDGE(0) EDGE(1) EDGE(2) EDGE(3) EDGE(4) EDGE(5) EDGE(6) EDGE(7)
                    BFL(0) BFL(1) BFL(2) BFL(3) BFL(4) BFL(5) BFL(6) BFL(7)
                }
                for (; e < cnt; ++e) {
                    EDGE(0)
                    BFL(0)
                }
                i += 64;
            }
            scat[dl][cur * 64 + c] = f2bf(acc);   // final flush
        }
        __syncthreads();
        // MFMA: [16,512] @ [512,64]; C/D col=lane&15, row=quad*4+r (m89/m91; R4/R6/R7-validated)
        const int m = lane & 15;
        const int quad = lane >> 4;
        const int n0 = wave * 16;
        f32x4 acc4 = {0.f, 0.f, 0.f, 0.f};
        const unsigned short* wrow = WT + (size_t)(n0 + m) * 512;
        #pragma unroll
        for (int kc = 0; kc < 16; ++kc) {
            short8 af = *(const short8*)&scat[m][kc * 32 + quad * 8];
            short8 bf = *(const short8*)(wrow + kc * 32 + quad * 8);
            acc4 = __builtin_amdgcn_mfma_f32_16x16x32_bf16(af, bf, acc4, 0, 0, 0);
        }
        const int col = n0 + m;
        const float bcol = bias[col];
        #pragma unroll
        for (int r = 0; r < 4; ++r) {
            int node = dbase + quad * 4 + r;
            float h = fmaxf(acc4[r] + bcol, 0.f);
            H[(size_t)node * 64 + col] = h;
            if (writeHb) Hb[(size_t)node * 64 + col] = f2bf(h);
        }
        __syncthreads();   // scat reused next tile
    }
}

__global__ __launch_bounds__(256, 4) void mega(MegaParams p) {
    cg::grid_group grid = cg::this_grid();
    __shared__ __align__(16) unsigned char smem[SMEM_BYTES];
    const int tid = threadIdx.x;
    const int lane = tid & 63;
    const int wave = tid >> 6;
    const int bid = blockIdx.x;
    const int nblocks = gridDim.x;
    const int gsz = nblocks * 256;
    const int gtid = bid * 256 + tid;

    // ---- P0: xb = bf16(x), WT1/WT2 transposes, zero cnt ----
    for (int i = gtid; i < N_NODES * 64; i += gsz) p.xb[i] = f2bf(p.x[i]);
    for (int i = gtid; i < 32768; i += gsz) {
        int n = i >> 9, k = i & 511;
        p.WT1[i] = f2bf(p.Wt1[k * 64 + n]);
        p.WT2[i] = f2bf(p.Wt2[k * 64 + n]);
    }
    for (int i = gtid; i < KEYS; i += gsz) p.cnt[i] = 0;
    grid.sync();

    // ---- P1: histogram over key = dst*8 + t ----
    for (int e = gtid; e < E_EDGES; e += gsz)
        atomicAdd(&p.cnt[p.dst[e] * 8 + p.tix[e]], 1);
    grid.sync();

    // ---- P2: per-chunk (512 keys) local exclusive scan + chunk totals ----
    {
        int* wsum = (int*)smem;
        for (int chunk = bid; chunk < NCHUNK; chunk += nblocks) {
            int base = chunk * 512 + tid * 2;
            int2 v = make_int2(0, 0);
            if (base < KEYS) v = *(const int2*)&p.cnt[base];
            int s = v.x + v.y;
            int sc = s;
            #pragma unroll
            for (int d = 1; d < 64; d <<= 1) {
                int o = __shfl_up(sc, d, 64);
                if (lane >= d) sc += o;
            }
            if (lane == 63) wsum[wave] = sc;
            __syncthreads();
            int wbase = (wave > 0 ? wsum[0] : 0) + (wave > 1 ? wsum[1] : 0) + (wave > 2 ? wsum[2] : 0);
            int tot = wsum[0] + wsum[1] + wsum[2] + wsum[3];
            __syncthreads();
            int excl = wbase + sc - s;
            if (base < KEYS) { int2 o2; o2.x = excl; o2.y = excl + v.x; *(int2*)&p.cnt[base] = o2; }
            if (tid == 0) p.bsum[chunk] = tot;
        }
    }
    grid.sync();

    // ---- P3+P4: every block scans bsum redundantly, applies offsets to its chunks ----
    {
        int* bpfx = (int*)smem;                   // NCHUNK ints
        int* wsum = (int*)(smem + 3136);
        int vals[4], tsum = 0;
        #pragma unroll
        for (int u = 0; u < 4; ++u) {
            int j = tid * 4 + u;
            vals[u] = (j < NCHUNK) ? p.bsum[j] : 0;
            tsum += vals[u];
        }
        int sc = tsum;
        #pragma unroll
        for (int d = 1; d < 64; d <<= 1) {
            int o = __shfl_up(sc, d, 64);
            if (lane >= d) sc += o;
        }
        if (lane == 63) wsum[wave] = sc;
        __syncthreads();
        int wbase = (wave > 0 ? wsum[0] : 0) + (wave > 1 ? wsum[1] : 0) + (wave > 2 ? wsum[2] : 0);
        int run = wbase + sc - tsum;
        #pragma unroll
        for (int u = 0; u < 4; ++u) {
            int j = tid * 4 + u;
            if (j < NCHUNK) bpfx[j] = run;
            run += vals[u];
        }
        __syncthreads();
        for (int chunk = bid; chunk < NCHUNK; chunk += nblocks) {
            int off = bpfx[chunk];
            int base = chunk * 512 + tid * 2;
            if (base < KEYS) {
                p.cnt[base] += off;
                p.cnt[base + 1] += off;
            }
        }
    }
    grid.sync();

    // ---- P5: scatter edges (cursor advance; afterwards cnt[k] = inclusive end) ----
    for (int e = gtid; e < E_EDGES; e += gsz) {
        int t = p.tix[e];
        int pos = atomicAdd(&p.cnt[p.dst[e] * 8 + t], 1);
        p.elist[pos] = p.src[e] | (t << 16);
    }
    grid.sync();

    // ---- P6: conv1 (xb -> h1, h1b) ----
    conv_phase(p.xb, p.WT1, p.bt1, p.cnt, p.elist, p.h1, p.h1b, 1, smem, lane, wave, bid, nblocks);
    grid.sync();

    // ---- P7: conv2 (h1b -> h2) ----
    conv_phase(p.h1b, p.WT2, p.bt2, p.cnt, p.elist, p.h2, p.h1b, 0, smem, lane, wave, bid, nblocks);
    grid.sync();

    // ---- P8: adversary MLP + h1 residual -> out (32 nodes/tile) ----
    {
        float (*sH)[68]  = (float(*)[68])smem;                 // 8704 B
        float (*sT)[132] = (float(*)[132])(smem + 8704);       // 16896 B
        for (int tile = bid; tile < NTILE_ADV; tile += nblocks) {
            const int nbase = tile * 32;
            {   // stage h2 tile
                int row = tid >> 3;
                int c8  = (tid & 7) * 8;
                int node = nbase + row;
                float4 a = make_float4(0.f, 0.f, 0.f, 0.f), b = a;
                if (node < N_NODES) {
                    a = *(const float4*)(p.h2 + (size_t)node * 64 + c8);
                    b = *(const float4*)(p.h2 + (size_t)node * 64 + c8 + 4);
                }
                *(float4*)&sH[row][c8] = a;
                *(float4*)&sH[row][c8 + 4] = b;
            }
            __syncthreads();
            {   // GEMM1: sT = relu(sH @ Wa1 + ba1)   [32,64]@[64,128]
                const int r0 = (tid >> 4) * 2;
                const int j0 = (tid & 15) * 8;
                float acc[2][8] = {};
                for (int k = 0; k < 64; ++k) {
                    float4 w0 = *(const float4*)(p.Wa1 + k * 128 + j0);
                    float4 w1 = *(const float4*)(p.Wa1 + k * 128 + j0 + 4);
                    float a0 = sH[r0][k], a1 = sH[r0 + 1][k];
                    float wv[8] = {w0.x, w0.y, w0.z, w0.w, w1.x, w1.y, w1.z, w1.w};
                    #pragma unroll
                    for (int j = 0; j < 8; ++j) {
                        acc[0][j] = fmaf(a0, wv[j], acc[0][j]);
                        acc[1][j] = fmaf(a1, wv[j], acc[1][j]);
                    }
                }
                float4 b0 = *(const float4*)(p.ba1 + j0);
                float4 b1 = *(const float4*)(p.ba1 + j0 + 4);
                float bv[8] = {b0.x, b0.y, b0.z, b0.w, b1.x, b1.y, b1.z, b1.w};
                #pragma unroll
                for (int i = 0; i < 2; ++i)
                    #pragma unroll
                    for (int j = 0; j < 8; ++j)
                        sT[r0 + i][j0 + j] = fmaxf(acc[i][j] + bv[j], 0.f);
            }
            __syncthreads();
            {   // GEMM2: out = sT @ Wa2 + ba2 + h1   [32,128]@[128,64]
                const int r0 = (tid >> 4) * 2;
                const int j0 = (tid & 15) * 4;
                float acc[2][4] = {};
                for (int k = 0; k < 128; ++k) {
                    float4 w = *(const float4*)(p.Wa2 + k * 64 + j0);
                    float a0 = sT[r0][k], a1 = sT[r0 + 1][k];
                    acc[0][0] = fmaf(a0, w.x, acc[0][0]); acc[0][1] = fmaf(a0, w.y, acc[0][1]);
                    acc[0][2] = fmaf(a0, w.z, acc[0][2]); acc[0][3] = fmaf(a0, w.w, acc[0][3]);
                    acc[1][0] = fmaf(a1, w.x, acc[1][0]); acc[1][1] = fmaf(a1, w.y, acc[1][1]);
                    acc[1][2] = fmaf(a1, w.z, acc[1][2]); acc[1][3] = fmaf(a1, w.w, acc[1][3]);
                }
                float4 b = *(const float4*)(p.ba2 + j0);
                #pragma unroll
                for (int i = 0; i < 2; ++i) {
                    int node = nbase + r0 + i;
                    if (node < N_NODES) {
                        float4 hh = *(const float4*)(p.h1 + (size_t)node * 64 + j0);
                        float4 r;
                        r.x = acc[i][0] + b.x + hh.x;
                        r.y = acc[i][1] + b.y + hh.y;
                        r.z = acc[i][2] + b.z + hh.z;
                        r.w = acc[i][3] + b.w + hh.w;
                        *(float4*)(p.out + (size_t)node * 64 + j0) = r;
                    }
                }
            }
            __syncthreads();   // sH/sT reused next tile
        }
    }
}

extern "C" void kernel_launch(void* const* d_in, const int* in_sizes, int n_in,
                              void* d_out, int out_size, void* d_ws, size_t ws_size,
                              hipStream_t stream) {
    MegaParams p;
    p.x   = (const float*)d_in[0];
    const int* ei = (const int*)d_in[1];
    p.tix = (const int*)d_in[2];
    p.Wt1 = (const float*)d_in[3];
    p.bt1 = (const float*)d_in[4];
    p.Wt2 = (const float*)d_in[5];
    p.bt2 = (const float*)d_in[6];
    p.Wa1 = (const float*)d_in[7];
    p.ba1 = (const float*)d_in[8];
    p.Wa2 = (const float*)d_in[9];
    p.ba2 = (const float*)d_in[10];
    p.out = (float*)d_out;
    p.src = ei;
    p.dst = ei + E_EDGES;

    // workspace (~44 MB)
    p.h1  = (float*)d_ws;                                        // [N,64] f32
    p.h2  = p.h1 + (size_t)N_NODES * 64;                         // [N,64] f32
    p.xb  = (unsigned short*)(p.h2 + (size_t)N_NODES * 64);      // [N,64] bf16
    p.h1b = p.xb + (size_t)N_NODES * 64;                         // [N,64] bf16
    p.WT1 = p.h1b + (size_t)N_NODES * 64;                        // [64,512] bf16
    p.WT2 = p.WT1 + 64 * 512;
    p.cnt = (int*)(p.WT2 + 64 * 512);                            // KEYS
    p.bsum = p.cnt + KEYS;                                       // NCHUNK (pad to 1024)
    p.elist = p.bsum + 1024;                                     // E packed (src | t<<16)

    int nb = 0;
    hipOccupancyMaxActiveBlocksPerMultiprocessor(&nb, (const void*)mega, 256, 0);
    if (nb < 1) nb = 1;
    if (nb > 4) nb = 4;
    int grid = nb * 256;

    void* args[] = { &p };
    hipLaunchCooperativeKernel((const void*)mega, dim3(grid), dim3(256), args, 0, stream);
}

// Round 9
// 353.888 us; speedup vs baseline: 2.3690x; 2.3690x over previous
//
#include <hip/hip_runtime.h>

#define N_NODES 50000
#define C_FEAT  64
#define E_EDGES 800000
#define KEYS    400000          // dst*8 + t
#define NBLK1   391             // ceil(KEYS/1024)
#define DPB     16              // dsts per conv block -> 16 MFMA rows
#define PBLK_X  1563            // x->bf16 cvt blocks (8 elems/thread)
#define PBLK_W  128             // W transpose blocks
#define PBLK_H  3125            // hist blocks

typedef __attribute__((ext_vector_type(8))) short short8;
typedef __attribute__((ext_vector_type(4))) float f32x4;

__device__ __forceinline__ float bf2f(unsigned short u) {
    union { unsigned int i; float f; } v; v.i = ((unsigned int)u) << 16; return v.f;
}
__device__ __forceinline__ unsigned short f2bf(float f) {
    union { float f; unsigned int i; } v; v.f = f;
    unsigned int r = v.i + 0x7fff + ((v.i >> 16) & 1);   // RNE
    return (unsigned short)(r >> 16);
}

// ---------------- prep (x->bf16 vec8, W->WT bf16) + hist, block-range fused ----------------
__global__ __launch_bounds__(256) void prep_hist(const float* __restrict__ x,
                                                 const float* __restrict__ W1,
                                                 const float* __restrict__ W2,
                                                 const int* __restrict__ dst,
                                                 const int* __restrict__ tix,
                                                 unsigned short* __restrict__ xb,
                                                 unsigned short* __restrict__ WT1,
                                                 unsigned short* __restrict__ WT2,
                                                 int* __restrict__ cnt) {
    const int b = blockIdx.x;
    if (b < PBLK_X) {
        int base = (b * 256 + threadIdx.x) * 8;            // N*64 = 3.2M, exact
        float4 a = *(const float4*)(x + base);
        float4 c = *(const float4*)(x + base + 4);
        short8 o;
        o[0] = (short)f2bf(a.x); o[1] = (short)f2bf(a.y);
        o[2] = (short)f2bf(a.z); o[3] = (short)f2bf(a.w);
        o[4] = (short)f2bf(c.x); o[5] = (short)f2bf(c.y);
        o[6] = (short)f2bf(c.z); o[7] = (short)f2bf(c.w);
        *(short8*)(xb + base) = o;
    } else if (b < PBLK_X + PBLK_W) {
        int i = (b - PBLK_X) * 256 + threadIdx.x;          // 32768
        int n = i >> 9, k = i & 511;
        WT1[i] = f2bf(W1[k * 64 + n]);
        WT2[i] = f2bf(W2[k * 64 + n]);
    } else {
        int e = (b - PBLK_X - PBLK_W) * 256 + threadIdx.x;
        if (e < E_EDGES) atomicAdd(&cnt[dst[e] * 8 + tix[e]], 1);
    }
}

// ---------------- scan1: int4/thread + wave shuffle scan (1024 keys/block) ----------------
__global__ __launch_bounds__(256) void scan1(int* __restrict__ arr, int* __restrict__ bsum) {
    __shared__ int wsum[4];
    const int tid = threadIdx.x;
    const int lane = tid & 63;
    const int wave = tid >> 6;
    const int i4 = blockIdx.x * 256 + tid;
    int4 v = make_int4(0, 0, 0, 0);
    const bool ok = (i4 * 4 < KEYS);                 // KEYS % 4 == 0
    if (ok) v = ((const int4*)arr)[i4];
    int s = v.x + v.y + v.z + v.w;
    int sc = s;
    #pragma unroll
    for (int d = 1; d < 64; d <<= 1) {
        int o = __shfl_up(sc, d, 64);
        if (lane >= d) sc += o;
    }
    if (lane == 63) wsum[wave] = sc;
    __syncthreads();
    int wbase = 0;
    #pragma unroll
    for (int w = 0; w < 4; ++w) wbase += (w < wave) ? wsum[w] : 0;
    int base = wbase + sc - s;
    int4 o;
    o.x = base;
    o.y = base + v.x;
    o.z = o.y + v.y;
    o.w = o.z + v.z;
    if (ok) ((int4*)arr)[i4] = o;
    if (tid == 255) bsum[blockIdx.x] = wbase + sc;   // block total
}

// ---------------- scan23: chunk b adds sum(bsum[0..b)) to its 1024 keys ----------------
__global__ __launch_bounds__(256) void scan23(int* __restrict__ arr, const int* __restrict__ bsum) {
    __shared__ int part[4];
    const int b = blockIdx.x;
    const int tid = threadIdx.x;
    const int lane = tid & 63;
    const int wave = tid >> 6;
    int s = 0;
    for (int j = tid; j < b; j += 256) s += bsum[j];
    #pragma unroll
    for (int d = 1; d < 64; d <<= 1) s += __shfl_xor(s, d, 64);
    if (lane == 0) part[wave] = s;
    __syncthreads();
    const int off = part[0] + part[1] + part[2] + part[3];
    const int i4 = b * 256 + tid;
    if (i4 * 4 < KEYS) {
        int4 v = ((const int4*)arr)[i4];
        v.x += off; v.y += off; v.z += off; v.w += off;
        ((int4*)arr)[i4] = v;
    }
}

// cursor advance; afterwards arr[k] == inclusive end. elist: src | t<<16 (t-sorted per dst)
__global__ __launch_bounds__(256) void scatter_edges(const int* __restrict__ src,
                                                     const int* __restrict__ dst,
                                                     const int* __restrict__ tix,
                                                     int* __restrict__ cursor,
                                                     int* __restrict__ elist) {
    int e = blockIdx.x * 256 + threadIdx.x;
    if (e >= E_EDGES) return;
    int t = tix[e];
    int pos = atomicAdd(&cursor[dst[e] * 8 + t], 1);
    elist[pos] = src[e] | (t << 16);
}

// ---------------- shared stage 1: t-sorted register-stream gather into scat ----------------
#define FLUSH(T, V)                                                                   \
    { int _t = (T);                                                                   \
      if (_t != cur) { scat[dl][cur * 64 + c] = f2bf(acc); acc = 0.f; cur = _t; }     \
      acc += (V); }

#define EDGE(K)                                                                       \
    int p##K = __builtin_amdgcn_readlane(pv, e + K);                                  \
    float v##K = bf2f(Xb[(size_t)(p##K & 0xffff) * 64 + c]);

__device__ __forceinline__ void gather_stage(const unsigned short* __restrict__ Xb,
                                             const int* __restrict__ segend,
                                             const int* __restrict__ elist,
                                             unsigned short (*scat)[520],
                                             int dbase, int wave, int lane) {
    const int c = lane;
    {   // zero own rows (wave-private in stage 1)
        short8 z = {};
        #pragma unroll
        for (int z4 = 0; z4 < 4; ++z4)
            *(short8*)&scat[wave * 4 + z4][lane * 8] = z;
    }
    // prefetch all 4 dsts' first windows before processing any (overlap elist RTs)
    int sbeg[4], send_[4], pvw[4];
    #pragma unroll
    for (int q = 0; q < 4; ++q) {
        const int d = dbase + wave * 4 + q;
        sbeg[q]  = (d == 0) ? 0 : segend[d * 8 - 1];
        send_[q] = segend[d * 8 + 7];
    }
    #pragma unroll
    for (int q = 0; q < 4; ++q)
        pvw[q] = (lane < send_[q] - sbeg[q]) ? elist[sbeg[q] + lane] : 0;

    #pragma unroll
    for (int q = 0; q < 4; ++q) {
        const int dl = wave * 4 + q;
        int i = sbeg[q];
        const int end = send_[q];
        int pv = pvw[q];
        int cur = 0;
        float acc = 0.f;
        while (i < end) {
            int cnt = end - i; cnt = (cnt > 64) ? 64 : cnt;
            int e = 0;
            for (; e + 7 < cnt; e += 8) {
                EDGE(0) EDGE(1) EDGE(2) EDGE(3) EDGE(4) EDGE(5) EDGE(6) EDGE(7)
                FLUSH(p0 >> 16, v0) FLUSH(p1 >> 16, v1)
                FLUSH(p2 >> 16, v2) FLUSH(p3 >> 16, v3)
                FLUSH(p4 >> 16, v4) FLUSH(p5 >> 16, v5)
                FLUSH(p6 >> 16, v6) FLUSH(p7 >> 16, v7)
            }
            for (; e < cnt; ++e) {
                EDGE(0)
                FLUSH(p0 >> 16, v0)
            }
            i += 64;
            if (i < end) pv = (lane < end - i) ? elist[i + lane] : 0;
        }
        scat[dl][cur * 64 + c] = f2bf(acc);   // final flush
    }
}

// ---------------- conv1: gather -> MFMA -> h1 (f32 + bf16) ----------------
__global__ __launch_bounds__(256, 8) void fused_conv1(const unsigned short* __restrict__ Xb,
                                                      const unsigned short* __restrict__ WT,  // [64,512] bf16
                                                      const float* __restrict__ bias,
                                                      const int* __restrict__ segend,
                                                      const int* __restrict__ elist,
                                                      float* __restrict__ H,
                                                      unsigned short* __restrict__ Hb) {
    __shared__ unsigned short scat[DPB][520];
    const int lane = threadIdx.x & 63;
    const int wave = threadIdx.x >> 6;
    const int dbase = blockIdx.x * DPB;

    gather_stage(Xb, segend, elist, scat, dbase, wave, lane);
    __syncthreads();

    // MFMA [16,512]@[512,64]; C/D col=lane&15, row=quad*4+r (m89/m91; R4/R6/R7-validated)
    const int m = lane & 15;
    const int quad = lane >> 4;
    const int n0 = wave * 16;
    f32x4 acc4 = {0.f, 0.f, 0.f, 0.f};
    const unsigned short* wrow = WT + (size_t)(n0 + m) * 512;
    #pragma unroll
    for (int kc = 0; kc < 16; ++kc) {
        short8 af = *(const short8*)&scat[m][kc * 32 + quad * 8];
        short8 bf = *(const short8*)(wrow + kc * 32 + quad * 8);
        acc4 = __builtin_amdgcn_mfma_f32_16x16x32_bf16(af, bf, acc4, 0, 0, 0);
    }
    const int col = n0 + m;
    const float bcol = bias[col];
    #pragma unroll
    for (int r = 0; r < 4; ++r) {
        int node = dbase + quad * 4 + r;
        float h = fmaxf(acc4[r] + bcol, 0.f);
        H[(size_t)node * 64 + col] = h;
        Hb[(size_t)node * 64 + col] = f2bf(h);
    }
}

// ---------------- conv2 + adversary MLP + residual, fully fused ----------------
// h2 tile (16x64) never leaves LDS: out = (relu(h2@Wa1+ba1)@Wa2+ba2) + h1
__global__ __launch_bounds__(256, 8) void conv2_adv(const unsigned short* __restrict__ Xb,   // h1b
                                                    const unsigned short* __restrict__ WT,   // WT2
                                                    const float* __restrict__ bias,          // bt2
                                                    const int* __restrict__ segend,
                                                    const int* __restrict__ elist,
                                                    const float* __restrict__ Wa1,  // [64,128]
                                                    const float* __restrict__ ba1,  // [128]
                                                    const float* __restrict__ Wa2,  // [128,64]
                                                    const float* __restrict__ ba2,  // [64]
                                                    const float* __restrict__ h1,   // [N,64] f32
                                                    float* __restrict__ out) {
    __shared__ __align__(16) unsigned char smem[16640];        // scat OR (sH 4352 | sT 8448)
    unsigned short (*scat)[520] = (unsigned short(*)[520])smem;
    float (*sH)[68]  = (float(*)[68])smem;
    float (*sT)[132] = (float(*)[132])(smem + 4352);
    const int tid = threadIdx.x;
    const int lane = tid & 63;
    const int wave = tid >> 6;
    const int dbase = blockIdx.x * DPB;

    gather_stage(Xb, segend, elist, scat, dbase, wave, lane);
    __syncthreads();

    // conv2 MFMA -> registers
    const int m = lane & 15;
    const int quad = lane >> 4;
    const int n0 = wave * 16;
    f32x4 acc4 = {0.f, 0.f, 0.f, 0.f};
    const unsigned short* wrow = WT + (size_t)(n0 + m) * 512;
    #pragma unroll
    for (int kc = 0; kc < 16; ++kc) {
        short8 af = *(const short8*)&scat[m][kc * 32 + quad * 8];
        short8 bf = *(const short8*)(wrow + kc * 32 + quad * 8);
        acc4 = __builtin_amdgcn_mfma_f32_16x16x32_bf16(af, bf, acc4, 0, 0, 0);
    }
    __syncthreads();                       // scat dead; overlay sH/sT

    {   // h2 tile -> sH (relu'd)
        const int col = n0 + m;
        const float bcol = bias[col];
        #pragma unroll
        for (int r = 0; r < 4; ++r)
            sH[quad * 4 + r][col] = fmaxf(acc4[r] + bcol, 0.f);
    }
    __syncthreads();

    {   // GEMM1: sT = relu(sH @ Wa1 + ba1)   [16,64]@[64,128]
        const int r = tid >> 4;
        const int j0 = (tid & 15) * 8;
        float acc[8] = {};
        for (int k = 0; k < 64; k += 4) {
            float4 a4 = *(const float4*)&sH[r][k];
            float av[4] = {a4.x, a4.y, a4.z, a4.w};
            #pragma unroll
            for (int kk = 0; kk < 4; ++kk) {
                float4 w0 = *(const float4*)(Wa1 + (k + kk) * 128 + j0);
                float4 w1 = *(const float4*)(Wa1 + (k + kk) * 128 + j0 + 4);
                acc[0] = fmaf(av[kk], w0.x, acc[0]); acc[1] = fmaf(av[kk], w0.y, acc[1]);
                acc[2] = fmaf(av[kk], w0.z, acc[2]); acc[3] = fmaf(av[kk], w0.w, acc[3]);
                acc[4] = fmaf(av[kk], w1.x, acc[4]); acc[5] = fmaf(av[kk], w1.y, acc[5]);
                acc[6] = fmaf(av[kk], w1.z, acc[6]); acc[7] = fmaf(av[kk], w1.w, acc[7]);
            }
        }
        float4 b0 = *(const float4*)(ba1 + j0);
        float4 b1 = *(const float4*)(ba1 + j0 + 4);
        float4 o0, o1;
        o0.x = fmaxf(acc[0] + b0.x, 0.f); o0.y = fmaxf(acc[1] + b0.y, 0.f);
        o0.z = fmaxf(acc[2] + b0.z, 0.f); o0.w = fmaxf(acc[3] + b0.w, 0.f);
        o1.x = fmaxf(acc[4] + b1.x, 0.f); o1.y = fmaxf(acc[5] + b1.y, 0.f);
        o1.z = fmaxf(acc[6] + b1.z, 0.f); o1.w = fmaxf(acc[7] + b1.w, 0.f);
        *(float4*)&sT[r][j0] = o0;
        *(float4*)&sT[r][j0 + 4] = o1;
    }
    __syncthreads();

    {   // GEMM2: out = sT @ Wa2 + ba2 + h1   [16,128]@[128,64]
        const int r = tid >> 4;
        const int j0 = (tid & 15) * 4;
        float acc[4] = {};
        for (int k = 0; k < 128; k += 4) {
            float4 a4 = *(const float4*)&sT[r][k];
            float av[4] = {a4.x, a4.y, a4.z, a4.w};
            #pragma unroll
            for (int kk = 0; kk < 4; ++kk) {
                float4 w = *(const float4*)(Wa2 + (k + kk) * 64 + j0);
                acc[0] = fmaf(av[kk], w.x, acc[0]); acc[1] = fmaf(av[kk], w.y, acc[1]);
                acc[2] = fmaf(av[kk], w.z, acc[2]); acc[3] = fmaf(av[kk], w.w, acc[3]);
            }
        }
        const int node = dbase + r;
        float4 b = *(const float4*)(ba2 + j0);
        float4 hh = *(const float4*)(h1 + (size_t)node * 64 + j0);
        float4 o;
        o.x = acc[0] + b.x + hh.x;
        o.y = acc[1] + b.y + hh.y;
        o.z = acc[2] + b.z + hh.z;
        o.w = acc[3] + b.w + hh.w;
        *(float4*)(out + (size_t)node * 64 + j0) = o;
    }
}

extern "C" void kernel_launch(void* const* d_in, const int* in_sizes, int n_in,
                              void* d_out, int out_size, void* d_ws, size_t ws_size,
                              hipStream_t stream) {
    const float* x   = (const float*)d_in[0];
    const int*   ei  = (const int*)d_in[1];
    const int*   tix = (const int*)d_in[2];
    const float* Wt1 = (const float*)d_in[3];
    const float* bt1 = (const float*)d_in[4];
    const float* Wt2 = (const float*)d_in[5];
    const float* bt2 = (const float*)d_in[6];
    const float* Wa1 = (const float*)d_in[7];
    const float* ba1 = (const float*)d_in[8];
    const float* Wa2 = (const float*)d_in[9];
    const float* ba2 = (const float*)d_in[10];
    float* out = (float*)d_out;

    const int* src = ei;
    const int* dst = ei + E_EDGES;

    // workspace (~31 MB)
    float* h1            = (float*)d_ws;                                  // [N,64] f32
    unsigned short* xb   = (unsigned short*)(h1 + (size_t)N_NODES * 64);  // [N,64] bf16
    unsigned short* h1b  = xb + (size_t)N_NODES * 64;                     // [N,64] bf16
    unsigned short* WT1  = h1b + (size_t)N_NODES * 64;                    // [64,512] bf16
    unsigned short* WT2  = WT1 + 64 * 512;
    int*   segend = (int*)(WT2 + 64 * 512);                               // KEYS
    int*   bsum   = segend + KEYS;                                        // 512
    int*   elist  = bsum + 512;                                           // E packed

    const int eBlk = (E_EDGES + 255) / 256;               // 3125
    const int cBlk = N_NODES / DPB;                       // 3125 (exact)

    hipMemsetAsync(segend, 0, KEYS * sizeof(int), stream);
    prep_hist<<<PBLK_X + PBLK_W + PBLK_H, 256, 0, stream>>>(x, Wt1, Wt2, dst, tix,
                                                            xb, WT1, WT2, segend);
    scan1<<<NBLK1, 256, 0, stream>>>(segend, bsum);
    scan23<<<NBLK1, 256, 0, stream>>>(segend, bsum);
    scatter_edges<<<eBlk, 256, 0, stream>>>(src, dst, tix, segend, elist);

    fused_conv1<<<cBlk, 256, 0, stream>>>(xb, WT1, bt1, segend, elist, h1, h1b);
    conv2_adv<<<cBlk, 256, 0, stream>>>(h1b, WT2, bt2, segend, elist,
                                        Wa1, ba1, Wa2, ba2, h1, out);
}

// Round 10
// 310.206 us; speedup vs baseline: 2.7026x; 1.1408x over previous
//
#include <hip/hip_runtime.h>

#define N_NODES 50000
#define C_FEAT  64
#define E_EDGES 800000
#define KEYS    400000          // dst*8 + t
#define NBLK1   391             // ceil(KEYS/1024)
#define DPB     16              // dsts per conv block -> 16 MFMA rows, 16 waves
#define PBLK_X  1563            // x->bf16 cvt blocks (8 elems/thread)
#define PBLK_W  128             // W transpose blocks
#define PBLK_H  3125            // hist blocks

typedef __attribute__((ext_vector_type(8))) short short8;
typedef __attribute__((ext_vector_type(4))) float f32x4;

__device__ __forceinline__ float bf2f(unsigned short u) {
    union { unsigned int i; float f; } v; v.i = ((unsigned int)u) << 16; return v.f;
}
__device__ __forceinline__ unsigned short f2bf(float f) {
    union { float f; unsigned int i; } v; v.f = f;
    unsigned int r = v.i + 0x7fff + ((v.i >> 16) & 1);   // RNE
    return (unsigned short)(r >> 16);
}

// ---------------- prep (x->bf16 vec8, W->WT bf16) + hist, block-range fused ----------------
__global__ __launch_bounds__(256) void prep_hist(const float* __restrict__ x,
                                                 const float* __restrict__ W1,
                                                 const float* __restrict__ W2,
                                                 const int* __restrict__ dst,
                                                 const int* __restrict__ tix,
                                                 unsigned short* __restrict__ xb,
                                                 unsigned short* __restrict__ WT1,
                                                 unsigned short* __restrict__ WT2,
                                                 int* __restrict__ cnt) {
    const int b = blockIdx.x;
    if (b < PBLK_X) {
        int base = (b * 256 + threadIdx.x) * 8;            // N*64 = 3.2M, exact
        float4 a = *(const float4*)(x + base);
        float4 c = *(const float4*)(x + base + 4);
        short8 o;
        o[0] = (short)f2bf(a.x); o[1] = (short)f2bf(a.y);
        o[2] = (short)f2bf(a.z); o[3] = (short)f2bf(a.w);
        o[4] = (short)f2bf(c.x); o[5] = (short)f2bf(c.y);
        o[6] = (short)f2bf(c.z); o[7] = (short)f2bf(c.w);
        *(short8*)(xb + base) = o;
    } else if (b < PBLK_X + PBLK_W) {
        int i = (b - PBLK_X) * 256 + threadIdx.x;          // 32768
        int n = i >> 9, k = i & 511;
        WT1[i] = f2bf(W1[k * 64 + n]);
        WT2[i] = f2bf(W2[k * 64 + n]);
    } else {
        int e = (b - PBLK_X - PBLK_W) * 256 + threadIdx.x;
        if (e < E_EDGES) atomicAdd(&cnt[dst[e] * 8 + tix[e]], 1);
    }
}

// ---------------- scan1: int4/thread + wave shuffle scan (1024 keys/block) ----------------
__global__ __launch_bounds__(256) void scan1(int* __restrict__ arr, int* __restrict__ bsum) {
    __shared__ int wsum[4];
    const int tid = threadIdx.x;
    const int lane = tid & 63;
    const int wave = tid >> 6;
    const int i4 = blockIdx.x * 256 + tid;
    int4 v = make_int4(0, 0, 0, 0);
    const bool ok = (i4 * 4 < KEYS);                 // KEYS % 4 == 0
    if (ok) v = ((const int4*)arr)[i4];
    int s = v.x + v.y + v.z + v.w;
    int sc = s;
    #pragma unroll
    for (int d = 1; d < 64; d <<= 1) {
        int o = __shfl_up(sc, d, 64);
        if (lane >= d) sc += o;
    }
    if (lane == 63) wsum[wave] = sc;
    __syncthreads();
    int wbase = 0;
    #pragma unroll
    for (int w = 0; w < 4; ++w) wbase += (w < wave) ? wsum[w] : 0;
    int base = wbase + sc - s;
    int4 o;
    o.x = base;
    o.y = base + v.x;
    o.z = o.y + v.y;
    o.w = o.z + v.z;
    if (ok) ((int4*)arr)[i4] = o;
    if (tid == 255) bsum[blockIdx.x] = wbase + sc;   // block total
}

// ---------------- scan23: chunk b adds sum(bsum[0..b)) to its 1024 keys ----------------
__global__ __launch_bounds__(256) void scan23(int* __restrict__ arr, const int* __restrict__ bsum) {
    __shared__ int part[4];
    const int b = blockIdx.x;
    const int tid = threadIdx.x;
    const int lane = tid & 63;
    const int wave = tid >> 6;
    int s = 0;
    for (int j = tid; j < b; j += 256) s += bsum[j];
    #pragma unroll
    for (int d = 1; d < 64; d <<= 1) s += __shfl_xor(s, d, 64);
    if (lane == 0) part[wave] = s;
    __syncthreads();
    const int off = part[0] + part[1] + part[2] + part[3];
    const int i4 = b * 256 + tid;
    if (i4 * 4 < KEYS) {
        int4 v = ((const int4*)arr)[i4];
        v.x += off; v.y += off; v.z += off; v.w += off;
        ((int4*)arr)[i4] = v;
    }
}

// cursor advance; afterwards arr[k] == inclusive end. elist: src | t<<16 (t-sorted per dst)
__global__ __launch_bounds__(256) void scatter_edges(const int* __restrict__ src,
                                                     const int* __restrict__ dst,
                                                     const int* __restrict__ tix,
                                                     int* __restrict__ cursor,
                                                     int* __restrict__ elist) {
    int e = blockIdx.x * 256 + threadIdx.x;
    if (e >= E_EDGES) return;
    int t = tix[e];
    int pos = atomicAdd(&cursor[dst[e] * 8 + t], 1);
    elist[pos] = src[e] | (t << 16);
}

// ---------------- fused conv: 1 wave = 1 dst, branchless flush, f32 scat, MFMA ----------------
// STEP stores the running acc unconditionally; the last store of each t-run is its
// final value (next run's first STEP lands after cur changed). No inner-loop branch.
#define EDGE(K)                                                                       \
    int p##K = __builtin_amdgcn_readlane(pv, e + K);                                  \
    float v##K = bf2f(Xb[(size_t)(p##K & 0xffff) * 64 + c]);
#define STEP(K)                                                                       \
    { int _t = p##K >> 16;                                                            \
      scat[wave][cur * 64 + c] = acc;                                                 \
      acc = (_t != cur) ? v##K : (acc + v##K);                                        \
      cur = _t; }

__global__ __launch_bounds__(1024, 8) void fused_conv(const unsigned short* __restrict__ Xb,  // [N,64] bf16
                                                      const unsigned short* __restrict__ WT,  // [64,512] bf16 (W^T)
                                                      const float* __restrict__ bias,
                                                      const int* __restrict__ segend,         // KEYS inclusive ends
                                                      const int* __restrict__ elist,          // src | t<<16
                                                      float* __restrict__ H,
                                                      unsigned short* __restrict__ Hb,
                                                      int writeHb) {
    __shared__ float scat[DPB][516];                 // 33 KB; f32 -> lane-private dword stores
    const int lane = threadIdx.x & 63;
    const int wave = threadIdx.x >> 6;               // 0..15 = local dst
    const int dbase = blockIdx.x * DPB;
    const int d = dbase + wave;
    const int c = lane;

    // zero own row (wave-private until the barrier)
    {
        float4 z = make_float4(0.f, 0.f, 0.f, 0.f);
        *(float4*)&scat[wave][lane * 8] = z;
        *(float4*)&scat[wave][lane * 8 + 4] = z;
    }

    int i   = (d == 0) ? 0 : segend[d * 8 - 1];
    const int end = segend[d * 8 + 7];
    int cur = 0;
    float acc = 0.f;
    while (i < end) {
        int cnt = end - i; cnt = (cnt > 64) ? 64 : cnt;
        int pv = (lane < cnt) ? elist[i + lane] : 0;   // one coalesced load per window
        int e = 0;
        for (; e + 7 < cnt; e += 8) {
            EDGE(0) EDGE(1) EDGE(2) EDGE(3) EDGE(4) EDGE(5) EDGE(6) EDGE(7)
            STEP(0) STEP(1) STEP(2) STEP(3) STEP(4) STEP(5) STEP(6) STEP(7)
        }
        for (; e < cnt; ++e) {
            EDGE(0)
            STEP(0)
        }
        i += 64;
    }
    scat[wave][cur * 64 + c] = acc;                  // final flush
    __syncthreads();

    // MFMA [16,512]@[512,64] on waves 0..3 (wave w owns cols w*16..); f32->bf16 inline.
    // C/D: col = lane&15, row = quad*4 + r  (m89/m91 mapping; R4/R6/R7-validated)
    if (wave < 4) {
        const int m = lane & 15;
        const int quad = lane >> 4;
        const int n0 = wave * 16;
        f32x4 acc4 = {0.f, 0.f, 0.f, 0.f};
        const unsigned short* wrow = WT + (size_t)(n0 + m) * 512;
        #pragma unroll
        for (int kc = 0; kc < 16; ++kc) {
            const float* ap = &scat[m][kc * 32 + quad * 8];
            short8 af;
            #pragma unroll
            for (int u = 0; u < 8; ++u) af[u] = (short)f2bf(ap[u]);
            short8 bf = *(const short8*)(wrow + kc * 32 + quad * 8);
            acc4 = __builtin_amdgcn_mfma_f32_16x16x32_bf16(af, bf, acc4, 0, 0, 0);
        }
        const int col = n0 + m;
        const float bcol = bias[col];
        #pragma unroll
        for (int r = 0; r < 4; ++r) {
            int node = dbase + quad * 4 + r;
            float h = fmaxf(acc4[r] + bcol, 0.f);
            H[(size_t)node * 64 + col] = h;
            if (writeHb) Hb[(size_t)node * 64 + col] = f2bf(h);
        }
    }
}

// ---------------- fused adversary MLP + h1 add (f32, 64-node tiles — R7-proven) ----------------
__global__ __launch_bounds__(256) void adv_fused(const float* __restrict__ h2,
                                                 const float* __restrict__ Wa1,  // [64,128]
                                                 const float* __restrict__ ba1,  // [128]
                                                 const float* __restrict__ Wa2,  // [128,64]
                                                 const float* __restrict__ ba2,  // [64]
                                                 const float* __restrict__ h1,
                                                 float* __restrict__ out) {
    __shared__ float sH[64][68];
    __shared__ float sT[64][132];
    const int nbase = blockIdx.x * 64;
    const int tid = threadIdx.x;
    const int j0 = (tid & 15) * 4;
    const int n0 = (tid >> 4) * 4;

    #pragma unroll
    for (int i = 0; i < 4; ++i) {
        int row  = (tid >> 4) + i * 16;
        int col4 = (tid & 15);
        int node = nbase + row;
        float4 v = make_float4(0.f, 0.f, 0.f, 0.f);
        if (node < N_NODES)
            v = *(const float4*)(h2 + (size_t)node * C_FEAT + col4 * 4);
        *(float4*)&sH[row][col4 * 4] = v;
    }
    __syncthreads();

    #pragma unroll
    for (int half = 0; half < 2; ++half) {
        const int j = half * 64 + j0;
        float acc[4][4] = {};
        #pragma unroll 8
        for (int k = 0; k < 64; ++k) {
            float4 w = *(const float4*)(Wa1 + k * 128 + j);
            float a0 = sH[n0 + 0][k];
            float a1 = sH[n0 + 1][k];
            float a2 = sH[n0 + 2][k];
            float a3 = sH[n0 + 3][k];
            acc[0][0] = fmaf(a0, w.x, acc[0][0]); acc[0][1] = fmaf(a0, w.y, acc[0][1]);
            acc[0][2] = fmaf(a0, w.z, acc[0][2]); acc[0][3] = fmaf(a0, w.w, acc[0][3]);
            acc[1][0] = fmaf(a1, w.x, acc[1][0]); acc[1][1] = fmaf(a1, w.y, acc[1][1]);
            acc[1][2] = fmaf(a1, w.z, acc[1][2]); acc[1][3] = fmaf(a1, w.w, acc[1][3]);
            acc[2][0] = fmaf(a2, w.x, acc[2][0]); acc[2][1] = fmaf(a2, w.y, acc[2][1]);
            acc[2][2] = fmaf(a2, w.z, acc[2][2]); acc[2][3] = fmaf(a2, w.w, acc[2][3]);
            acc[3][0] = fmaf(a3, w.x, acc[3][0]); acc[3][1] = fmaf(a3, w.y, acc[3][1]);
            acc[3][2] = fmaf(a3, w.z, acc[3][2]); acc[3][3] = fmaf(a3, w.w, acc[3][3]);
        }
        float4 b1 = *(const float4*)(ba1 + j);
        #pragma unroll
        for (int i = 0; i < 4; ++i) {
            float4 r;
            r.x = fmaxf(acc[i][0] + b1.x, 0.f);
            r.y = fmaxf(acc[i][1] + b1.y, 0.f);
            r.z = fmaxf(acc[i][2] + b1.z, 0.f);
            r.w = fmaxf(acc[i][3] + b1.w, 0.f);
            *(float4*)&sT[n0 + i][j] = r;
        }
    }
    __syncthreads();

    float acc[4][4] = {};
    #pragma unroll 8
    for (int k = 0; k < 128; ++k) {
        float4 w = *(const float4*)(Wa2 + k * 64 + j0);
        float a0 = sT[n0 + 0][k];
        float a1 = sT[n0 + 1][k];
        float a2 = sT[n0 + 2][k];
        float a3 = sT[n0 + 3][k];
        acc[0][0] = fmaf(a0, w.x, acc[0][0]); acc[0][1] = fmaf(a0, w.y, acc[0][1]);
        acc[0][2] = fmaf(a0, w.z, acc[0][2]); acc[0][3] = fmaf(a0, w.w, acc[0][3]);
        acc[1][0] = fmaf(a1, w.x, acc[1][0]); acc[1][1] = fmaf(a1, w.y, acc[1][1]);
        acc[1][2] = fmaf(a1, w.z, acc[1][2]); acc[1][3] = fmaf(a1, w.w, acc[1][3]);
        acc[2][0] = fmaf(a2, w.x, acc[2][0]); acc[2][1] = fmaf(a2, w.y, acc[2][1]);
        acc[2][2] = fmaf(a2, w.z, acc[2][2]); acc[2][3] = fmaf(a2, w.w, acc[2][3]);
        acc[3][0] = fmaf(a3, w.x, acc[3][0]); acc[3][1] = fmaf(a3, w.y, acc[3][1]);
        acc[3][2] = fmaf(a3, w.z, acc[3][2]); acc[3][3] = fmaf(a3, w.w, acc[3][3]);
    }
    float4 b2 = *(const float4*)(ba2 + j0);
    #pragma unroll
    for (int i = 0; i < 4; ++i) {
        int node = nbase + n0 + i;
        if (node < N_NODES) {
            float4 hh = *(const float4*)(h1 + (size_t)node * C_FEAT + j0);
            float4 r;
            r.x = acc[i][0] + b2.x + hh.x;
            r.y = acc[i][1] + b2.y + hh.y;
            r.z = acc[i][2] + b2.z + hh.z;
            r.w = acc[i][3] + b2.w + hh.w;
            *(float4*)(out + (size_t)node * C_FEAT + j0) = r;
        }
    }
}

extern "C" void kernel_launch(void* const* d_in, const int* in_sizes, int n_in,
                              void* d_out, int out_size, void* d_ws, size_t ws_size,
                              hipStream_t stream) {
    const float* x   = (const float*)d_in[0];
    const int*   ei  = (const int*)d_in[1];
    const int*   tix = (const int*)d_in[2];
    const float* Wt1 = (const float*)d_in[3];
    const float* bt1 = (const float*)d_in[4];
    const float* Wt2 = (const float*)d_in[5];
    const float* bt2 = (const float*)d_in[6];
    const float* Wa1 = (const float*)d_in[7];
    const float* ba1 = (const float*)d_in[8];
    const float* Wa2 = (const float*)d_in[9];
    const float* ba2 = (const float*)d_in[10];
    float* out = (float*)d_out;

    const int* src = ei;
    const int* dst = ei + E_EDGES;

    // workspace (~44 MB)
    float* h1            = (float*)d_ws;                                  // [N,64] f32
    float* h2            = h1 + (size_t)N_NODES * 64;                     // [N,64] f32
    unsigned short* xb   = (unsigned short*)(h2 + (size_t)N_NODES * 64);  // [N,64] bf16
    unsigned short* h1b  = xb + (size_t)N_NODES * 64;                     // [N,64] bf16
    unsigned short* WT1  = h1b + (size_t)N_NODES * 64;                    // [64,512] bf16
    unsigned short* WT2  = WT1 + 64 * 512;
    int*   segend = (int*)(WT2 + 64 * 512);                               // KEYS
    int*   bsum   = segend + KEYS;                                        // 512
    int*   elist  = bsum + 512;                                           // E packed

    const int eBlk = (E_EDGES + 255) / 256;               // 3125
    const int cBlk = N_NODES / DPB;                       // 3125 (exact)
    const int aBlk = (N_NODES + 63) / 64;                 // 782

    hipMemsetAsync(segend, 0, KEYS * sizeof(int), stream);
    prep_hist<<<PBLK_X + PBLK_W + PBLK_H, 256, 0, stream>>>(x, Wt1, Wt2, dst, tix,
                                                            xb, WT1, WT2, segend);
    scan1<<<NBLK1, 256, 0, stream>>>(segend, bsum);
    scan23<<<NBLK1, 256, 0, stream>>>(segend, bsum);
    scatter_edges<<<eBlk, 256, 0, stream>>>(src, dst, tix, segend, elist);

    fused_conv<<<cBlk, 1024, 0, stream>>>(xb,  WT1, bt1, segend, elist, h1, h1b, 1);
    fused_conv<<<cBlk, 1024, 0, stream>>>(h1b, WT2, bt2, segend, elist, h2, h1b, 0);

    adv_fused<<<aBlk, 256, 0, stream>>>(h2, Wa1, ba1, Wa2, ba2, h1, out);
}